// Round 9
// baseline (651.920 us; speedup 1.0000x reference)
//
#include <hip/hip_runtime.h>
#include <stdint.h>

typedef unsigned int u32;
typedef unsigned long long u64;

#define NPTS 8192
#define NTRI 2080            // 64*65/2 triangular 128x128 tiles
#define NSLICE 16u

// ws byte offsets
#define WS_HIST    0u        // u32[16][1024] sliced coarse hist = 65536 B (dead after sel1)
#define WS_CAND    65536u    // u64[CAP] = 524288 B -> 589824
#define CAP        65536u    // expected ~36K same-bin candidates -> 1.8x margin
#define WS_STATE   589824u   // u32[8]: 0:cb0 1:cb1 2:base0 3:base1 4:ctr 5:maxraw0 6:minraw1
#define WS_DC      589856u
#define WS_SQ      590336u   // float[8192] -> 623104
#define WS_ROWMAX  623104u   // u32[8192] -> 655872
#define WS_RHOD    655872u   // double[8192] -> 721408
#define WS_MINKEY  721408u   // u64[8192] -> 786944
#define WS_S       1048576ull  // float[NTRI*16384] d2 store (byte-identical to r4-r7)

#define K_RANK 1342177u  // floor(0.02f * fp32(N*N-1)); frac = 0.25 (validated r1-r7)

__device__ __forceinline__ u64 umin64(u64 a, u64 b) { return a < b ? a : b; }

__device__ __forceinline__ void tri_decode(int t, int& bi, int& bj) {
  int a = (int)((sqrtf(8.0f * (float)t + 1.0f) - 1.0f) * 0.5f);
  while ((a + 1) * (a + 2) / 2 <= t) ++a;
  while (a * (a + 1) / 2 > t) --a;
  int b = t - a * (a + 1) / 2;
  bi = 63 - a; bj = 63 - b;   // a>=b -> bi<=bj
}

// 8192 fine bins over key=floor(d2*2^20): fine bin f <=> d2 in [f/32,(f+1)/32).
// Coarse bin = f>>3 <=> d2 in [cb/4,(cb+1)/4) -- dyadic, exact.
__device__ __forceinline__ u32 bin_of(float d2v) {
  float kf = fminf(d2v * 1048576.0f, 2147483520.0f);
  return min(((u32)kf) >> 15, 8191u);
}

// exclusive prefix over 1024 threads (16 waves of 64). aux: u32[40] LDS.
__device__ __forceinline__ u32 block_exscan_1024(u32 v, u32* aux, u32& total) {
  const int lane = threadIdx.x & 63, wave = threadIdx.x >> 6;
  u32 inc = v;
#pragma unroll
  for (int m = 1; m < 64; m <<= 1) {
    u32 o = (u32)__shfl_up((int)inc, m, 64);
    if (lane >= m) inc += o;
  }
  if (lane == 63) aux[wave] = inc;
  __syncthreads();
  if (wave == 0) {
    u32 wv = (lane < 16) ? aux[lane] : 0u;
    u32 winc = wv;
#pragma unroll
    for (int m = 1; m < 16; m <<= 1) {
      u32 o = (u32)__shfl_up((int)winc, m, 64);
      if (lane >= m) winc += o;
    }
    if (lane < 16) aux[16 + lane] = winc - wv;
    if (lane == 15) aux[33] = winc;
  }
  __syncthreads();
  total = aux[33];
  return aux[16 + wave] + (inc - v);
}

// ===== r2-exact tile128 (validated r4-r7) =====
__device__ __forceinline__ void tile128(
    const float* __restrict__ X, const float* __restrict__ sq,
    float (*As)[132], float (*Bs)[132],
    int bi, int bj, int tx, int ty, float (&d2)[8][8])
{
  const int tid = threadIdx.x;
  const float4* Xv = reinterpret_cast<const float4*>(X);
  float acc[8][8] = {};
  for (int ph = 0; ph < 2; ++ph) {
    if (ph) __syncthreads();
#pragma unroll
    for (int rep = 0; rep < 4; ++rep) {
      int idx = rep * 256 + tid;
      int i   = idx >> 3;
      int q   = idx & 7;
      int col = (((i >> 2) ^ (q >> 1)) << 2) | (i & 3);
      float4 va = Xv[(bi * 128 + i) * 16 + ph * 8 + q];
      As[4*q+0][col] = va.x; As[4*q+1][col] = va.y; As[4*q+2][col] = va.z; As[4*q+3][col] = va.w;
      float4 vb = Xv[(bj * 128 + i) * 16 + ph * 8 + q];
      Bs[4*q+0][col] = vb.x; Bs[4*q+1][col] = vb.y; Bs[4*q+2][col] = vb.z; Bs[4*q+3][col] = vb.w;
    }
    __syncthreads();
#pragma unroll
    for (int c8 = 0; c8 < 4; ++c8) {
#pragma unroll
      for (int u = 0; u < 8; ++u) {
        int k = c8 * 8 + u;
        float4 a0 = *reinterpret_cast<const float4*>(&As[k][((2*ty+0) ^ c8) << 2]);
        float4 a1 = *reinterpret_cast<const float4*>(&As[k][((2*ty+1) ^ c8) << 2]);
        float4 b0 = *reinterpret_cast<const float4*>(&Bs[k][((2*tx+0) ^ c8) << 2]);
        float4 b1 = *reinterpret_cast<const float4*>(&Bs[k][((2*tx+1) ^ c8) << 2]);
        float a[8] = {a0.x,a0.y,a0.z,a0.w,a1.x,a1.y,a1.z,a1.w};
        float b[8] = {b0.x,b0.y,b0.z,b0.w,b1.x,b1.y,b1.z,b1.w};
#pragma unroll
        for (int r = 0; r < 8; ++r)
#pragma unroll
          for (int c = 0; c < 8; ++c)
            acc[r][c] = fmaf(a[r], b[c], acc[r][c]);
      }
    }
  }
  float sqa[8], sqb[8];
#pragma unroll
  for (int r = 0; r < 8; ++r) sqa[r] = sq[bi * 128 + ty * 8 + r];
#pragma unroll
  for (int c = 0; c < 8; ++c) sqb[c] = sq[bj * 128 + tx * 8 + c];
#pragma unroll
  for (int r = 0; r < 8; ++r)
#pragma unroll
    for (int c = 0; c < 8; ++c)
      d2[r][c] = fmaxf((sqa[r] + sqb[c]) - 2.0f * acc[r][c], 0.0f);
}

// ===== per-float4 element processors (q in [0,16): r=q>>1, c0=(q&1)*4) =====
// Streaming order == legacy (r,c) order per accumulator -> bit-identical sums.

__device__ __forceinline__ void rho_elem(
    float4 v, int q, float inv2, bool diag, int ig0, int jg0,
    float* rA, float* rB)
{
  int r = q >> 1, c0 = (q & 1) * 4;
  float e[4] = {v.x, v.y, v.z, v.w};
#pragma unroll
  for (int j = 0; j < 4; ++j) {
    float t = __expf(-(e[j] * inv2));
    if (!diag) { rA[r] += t; rB[c0 + j] += t; }
    else {
      int ig = ig0 + r, jg = jg0 + c0 + j;
      if (ig < jg) { rA[r] += t; rB[c0 + j] += t; }
      else if (ig == jg) rA[r] += t;
    }
  }
}

__device__ __forceinline__ void delta_elem(
    float4 v, int q, bool offd, int ig0, int jg0,
    const float* ri, const float* rj, u64* bA, u64* bB)
{
  int r = q >> 1, c0 = (q & 1) * 4;
  float e[4] = {v.x, v.y, v.z, v.w};
#pragma unroll
  for (int j = 0; j < 4; ++j) {
    int c = c0 + j;
    int ig = ig0 + r, jg = jg0 + c;
    if (offd || ig < jg) {
      u64 kb = ((u64)__float_as_uint(sqrtf(e[j]))) << 32;  // dist-domain ties == reference
      if (rj[c] > ri[r]) bA[r] = umin64(bA[r], kb | (u64)(u32)jg);
      if (ri[r] > rj[c]) bB[c] = umin64(bB[c], kb | (u64)(u32)ig);
    }
  }
}

// ===== shared reductions =====

__device__ __forceinline__ void rho_finish(
    float* rA, float* rB, int bi, int bj, int ig0, u32* __restrict__ ws,
    double (*redB)[128])
{
  const int tid = threadIdx.x;
  const int wv = tid >> 6, lane = tid & 63;
  double* rhod = reinterpret_cast<double*>((char*)ws + WS_RHOD);
#pragma unroll
  for (int m = 1; m <= 8; m <<= 1)
#pragma unroll
    for (int r = 0; r < 8; ++r) rA[r] += __shfl_xor(rA[r], m);
  if ((tid & 15) == 0)
#pragma unroll
    for (int r = 0; r < 8; ++r) atomicAdd(&rhod[ig0 + r], (double)rA[r]);
#pragma unroll
  for (int m = 16; m <= 32; m <<= 1)
#pragma unroll
    for (int c = 0; c < 8; ++c) rB[c] += __shfl_xor(rB[c], m);
  if (lane < 16)
#pragma unroll
    for (int c = 0; c < 8; ++c) redB[wv][(tid & 15) * 8 + c] = (double)rB[c];
  __syncthreads();
  if (tid < 128) {
    double s = redB[0][tid] + redB[1][tid] + redB[2][tid] + redB[3][tid];
    atomicAdd(&rhod[bj * 128 + tid], s);
  }
}

__device__ __forceinline__ void delta_finish(
    u64* bA, u64* bB, int bi, int bj, int ig0, u32* __restrict__ ws,
    u64 (*redM)[128])
{
  const int tid = threadIdx.x;
  const int wv = tid >> 6, lane = tid & 63;
  u64* mk = reinterpret_cast<u64*>((char*)ws + WS_MINKEY);
#pragma unroll
  for (int m = 1; m <= 8; m <<= 1)
#pragma unroll
    for (int r = 0; r < 8; ++r) bA[r] = umin64(bA[r], __shfl_xor(bA[r], m));
  if ((tid & 15) == 0)
#pragma unroll
    for (int r = 0; r < 8; ++r) if (bA[r] != ~0ull) atomicMin(&mk[ig0 + r], bA[r]);
#pragma unroll
  for (int m = 16; m <= 32; m <<= 1)
#pragma unroll
    for (int c = 0; c < 8; ++c) bB[c] = umin64(bB[c], __shfl_xor(bB[c], m));
  if (lane < 16)
#pragma unroll
    for (int c = 0; c < 8; ++c) redM[wv][(tid & 15) * 8 + c] = bB[c];
  __syncthreads();
  if (tid < 128) {
    u64 m = umin64(umin64(redM[0][tid], redM[1][tid]), umin64(redM[2][tid], redM[3][tid]));
    if (m != ~0ull) atomicMin(&mk[bj * 128 + tid], m);
  }
}

// collect: same-coarse-bin -> ballot-append candidates; straddle -> max/min raw only
__device__ __forceinline__ void collect_elems(
    float d2v, u32 w, u32 cb0, u32 cb1, bool same,
    u32* ctr, u64* cand, u32& mx, u32& mn)
{
  u32 cb = bin_of(d2v) >> 3;
  u32 raw = __float_as_uint(d2v);
  if (same) {
    bool ic = w && (cb == cb0);
    u64 m = __ballot(ic);
    if (m) {
      int lane = threadIdx.x & 63;
      int leader = __ffsll((long long)m) - 1;
      u32 base = 0;
      if (lane == leader) base = atomicAdd(ctr, (u32)__popcll(m));
      base = (u32)__shfl((int)base, leader);
      if (ic) {
        u32 pos = base + (u32)__popcll(m & ((1ull << lane) - 1ull));
        if (pos < CAP) cand[pos] = (((u64)raw) << 32) | (u64)w;
      }
    }
  } else {
    if (w && cb == cb0) mx = max(mx, raw);   // value(K) = max raw in cb0
    if (w && cb == cb1) mn = min(mn, raw);   // value(K+1) = min raw in cb1
  }
}

// ===== kernels =====

__global__ __launch_bounds__(256) void k_init(u32* __restrict__ ws) {
  u32 t = blockIdx.x * 256u + threadIdx.x;   // 16384 threads
  ws[t] = 0u;                                // coarse sliced hist (16K u32)
  if (t < 8u) ws[WS_STATE / 4 + t] = (t == 6u) ? 0xFFFFFFFFu : 0u;
  if (t < 8192u) {
    ws[WS_ROWMAX / 4 + t] = 0u;
    reinterpret_cast<double*>((char*)ws + WS_RHOD)[t] = 0.0;
    reinterpret_cast<u64*>((char*)ws + WS_MINKEY)[t] = ~0ull;
  }
}

__global__ __launch_bounds__(256) void k_sq(const float* __restrict__ X, float* __restrict__ sq) {
  int i = blockIdx.x * 256 + threadIdx.x;
  const float4* row = reinterpret_cast<const float4*>(X + i * 64);
  float s = 0.f;
#pragma unroll
  for (int q = 0; q < 16; ++q) {
    float4 v = row[q];
    s = fmaf(v.x, v.x, s); s = fmaf(v.y, v.y, s);
    s = fmaf(v.z, v.z, s); s = fmaf(v.w, v.w, s);
  }
  sq[i] = s;
}

// compute pass: d2 + store + rowmax + 8192-bin LDS hist -> COARSE (1024-bin) sliced flush
__global__ __launch_bounds__(256, 4) void k_hist(
    const float* __restrict__ X, const float* __restrict__ sq,
    u32* __restrict__ ws, float4* __restrict__ S4)
{
  __shared__ __align__(16) char smem[33792];
  float (*As)[132] = reinterpret_cast<float(*)[132]>(smem);
  float (*Bs)[132] = reinterpret_cast<float(*)[132]>(smem + 16896);
  u32* h = reinterpret_cast<u32*>(smem);           // 8192 u32 reused post-compute
  int bi, bj; tri_decode(blockIdx.x, bi, bj);
  const int tid = threadIdx.x;
  const int tx = tid & 15, ty = tid >> 4;
  float d2[8][8];
  tile128(X, sq, As, Bs, bi, bj, tx, ty, d2);

  if (S4) {
    float4* tS = S4 + (size_t)blockIdx.x * 4096 + tid;
#pragma unroll
    for (int q = 0; q < 16; ++q) {
      int r = q >> 1, c0 = (q & 1) * 4;
      tS[q * 256] = make_float4(d2[r][c0+0], d2[r][c0+1], d2[r][c0+2], d2[r][c0+3]);
    }
  }

  const int ig0 = bi * 128 + ty * 8, jg0 = bj * 128 + tx * 8;
  u32* rowmax = ws + WS_ROWMAX / 4;
  u32 rmA[8], rmB[8];
#pragma unroll
  for (int r = 0; r < 8; ++r) {
    u32 m = 0;
#pragma unroll
    for (int c = 0; c < 8; ++c) m = max(m, __float_as_uint(d2[r][c]));
    rmA[r] = m;
  }
#pragma unroll
  for (int c = 0; c < 8; ++c) {
    u32 m = 0;
#pragma unroll
    for (int r = 0; r < 8; ++r) m = max(m, __float_as_uint(d2[r][c]));
    rmB[c] = m;
  }
#pragma unroll
  for (int m = 1; m <= 8; m <<= 1)
#pragma unroll
    for (int r = 0; r < 8; ++r) rmA[r] = max(rmA[r], (u32)__shfl_xor((int)rmA[r], m));
  if ((tid & 15) == 0)
#pragma unroll
    for (int r = 0; r < 8; ++r) atomicMax(&rowmax[ig0 + r], rmA[r]);
#pragma unroll
  for (int m = 16; m <= 32; m <<= 1)
#pragma unroll
    for (int c = 0; c < 8; ++c) rmB[c] = max(rmB[c], (u32)__shfl_xor((int)rmB[c], m));
  if ((tid & 48) == 0)
#pragma unroll
    for (int c = 0; c < 8; ++c) atomicMax(&rowmax[jg0 + c], rmB[c]);

  __syncthreads();
  for (int i = tid; i < 8192; i += 256) h[i] = 0;
  __syncthreads();
  const bool offd = (bi < bj);
#pragma unroll
  for (int r = 0; r < 8; ++r)
#pragma unroll
    for (int c = 0; c < 8; ++c) {
      int ig = ig0 + r, jg = jg0 + c;
      u32 w = offd ? 2u : (ig < jg ? 2u : (ig == jg ? 1u : 0u));
      if (w) atomicAdd(&h[bin_of(d2[r][c])], w);
    }
  __syncthreads();
  u32* Hs = ws + (blockIdx.x & 15) * 1024;         // coarse flush: 1024 atomics/block (was 8192)
  for (int cb = tid; cb < 1024; cb += 256) {
    u32 s = 0;
#pragma unroll
    for (int e = 0; e < 8; ++e) s += h[cb * 8 + e];
    if (s) atomicAdd(&Hs[cb], s);
  }
}

// one coarse bin per thread; exscan; locate ranks K, K+1
__global__ __launch_bounds__(1024) void k_sel1(u32* __restrict__ ws) {
  __shared__ u32 aux[40];
  const int t = threadIdx.x;
  const u32* H = ws;
  u32* st = ws + WS_STATE / 4;
  u32 v = 0;
#pragma unroll
  for (u32 sl = 0; sl < NSLICE; ++sl) v += H[sl * 1024u + (u32)t];
  u32 total;
  u32 cum = block_exscan_1024(v, aux, total);
  if (cum <= K_RANK && K_RANK < cum + v)           { st[0] = (u32)t; st[2] = cum; }
  if (cum <= K_RANK + 1u && K_RANK + 1u < cum + v) { st[1] = (u32)t; st[3] = cum; }
}

__global__ __launch_bounds__(256) void k_collectS(
    const float4* __restrict__ S4, u32* __restrict__ ws)
{
  int bi, bj; tri_decode(blockIdx.x, bi, bj);
  const int tid = threadIdx.x;
  const int tx = tid & 15, ty = tid >> 4;
  u32* st = ws + WS_STATE / 4;
  const u32 cb0 = st[0], cb1 = st[1];
  const bool same = (cb0 == cb1);
  u32* ctr = st + 4;
  u64* cand = reinterpret_cast<u64*>((char*)ws + WS_CAND);
  const int ig0 = bi * 128 + ty * 8, jg0 = bj * 128 + tx * 8;
  const bool offd = (bi < bj);
  const float4* tS = S4 + (size_t)blockIdx.x * 4096 + tid;
  u32 mx = 0u, mn = 0xFFFFFFFFu;
#pragma unroll 4
  for (int q = 0; q < 16; ++q) {
    float4 v = tS[q * 256];
    int r = q >> 1, c0 = (q & 1) * 4;
    float e[4] = {v.x, v.y, v.z, v.w};
#pragma unroll
    for (int j = 0; j < 4; ++j) {
      int ig = ig0 + r, jg = jg0 + c0 + j;
      u32 w = offd ? 2u : (ig < jg ? 2u : (ig == jg ? 1u : 0u));
      collect_elems(e[j], w, cb0, cb1, same, ctr, cand, mx, mn);
    }
  }
  if (!same) {   // wave-reduce then 1 atomic per wave
#pragma unroll
    for (int m = 1; m <= 32; m <<= 1) {
      mx = max(mx, (u32)__shfl_xor((int)mx, m));
      mn = min(mn, (u32)__shfl_xor((int)mn, m));
    }
    if ((tid & 63) == 0) { atomicMax(&st[5], mx); atomicMin(&st[6], mn); }
  }
}

__global__ __launch_bounds__(256, 4) void k_collectR(
    const float* __restrict__ X, const float* __restrict__ sq, u32* __restrict__ ws)
{
  __shared__ __align__(16) char smem[33792];
  float (*As)[132] = reinterpret_cast<float(*)[132]>(smem);
  float (*Bs)[132] = reinterpret_cast<float(*)[132]>(smem + 16896);
  int bi, bj; tri_decode(blockIdx.x, bi, bj);
  const int tid = threadIdx.x;
  const int tx = tid & 15, ty = tid >> 4;
  float d2[8][8];
  tile128(X, sq, As, Bs, bi, bj, tx, ty, d2);
  u32* st = ws + WS_STATE / 4;
  const u32 cb0 = st[0], cb1 = st[1];
  const bool same = (cb0 == cb1);
  u32* ctr = st + 4;
  u64* cand = reinterpret_cast<u64*>((char*)ws + WS_CAND);
  const int ig0 = bi * 128 + ty * 8, jg0 = bj * 128 + tx * 8;
  const bool offd = (bi < bj);
  u32 mx = 0u, mn = 0xFFFFFFFFu;
#pragma unroll
  for (int q = 0; q < 16; ++q) {
    int r = q >> 1, c0 = (q & 1) * 4;
#pragma unroll
    for (int j = 0; j < 4; ++j) {
      int ig = ig0 + r, jg = jg0 + c0 + j;
      u32 w = offd ? 2u : (ig < jg ? 2u : (ig == jg ? 1u : 0u));
      collect_elems(d2[r][c0 + j], w, cb0, cb1, same, ctr, cand, mx, mn);
    }
  }
  if (!same) {
#pragma unroll
    for (int m = 1; m <= 32; m <<= 1) {
      mx = max(mx, (u32)__shfl_xor((int)mx, m));
      mn = min(mn, (u32)__shfl_xor((int)mn, m));
    }
    if ((tid & 63) == 0) { atomicMax(&st[5], mx); atomicMin(&st[6], mn); }
  }
}

// zoom: LDS hist refinement within coarse bin cb; raw span ~32K -> 2 iterations
__device__ u32 zoom(const u64* __restrict__ cand, u32 M, u32 cb, u32 base, u32 rank,
                    u32* h, u32* aux) {
  u32 lo = __float_as_uint((float)cb * 0.25f);
  u32 hi = __float_as_uint((float)(cb + 1) * 0.25f);
  u32 need = rank - base;
  while (hi - lo > 1u) {
    u32 range = hi - lo;
    int sh = 0;
    while ((8192u << sh) < range) ++sh;
    for (u32 i = threadIdx.x; i < 8192u; i += 1024u) h[i] = 0;
    __syncthreads();
    for (u32 i = threadIdx.x; i < M; i += 1024u) {
      u64 cw = cand[i];
      u32 raw = (u32)(cw >> 32);
      if (raw >= lo && raw < hi) atomicAdd(&h[(raw - lo) >> sh], (u32)(cw & 3u));
    }
    __syncthreads();
    u32 loc[8];
    u32 s = 0;
#pragma unroll
    for (int e = 0; e < 8; ++e) { loc[e] = h[threadIdx.x * 8u + e]; s += loc[e]; }
    u32 total;
    u32 pre = block_exscan_1024(s, aux, total);
    if (need >= pre && need < pre + s) {
      u32 cum = pre;
#pragma unroll
      for (int e = 0; e < 8; ++e) {
        if (need >= cum && need < cum + loc[e]) { aux[36] = threadIdx.x * 8u + (u32)e; aux[37] = cum; }
        cum += loc[e];
      }
    }
    __syncthreads();
    u32 bb = aux[36], sub = aux[37];
    need -= sub;
    u32 nlo = lo + (bb << sh);
    hi = min(hi, nlo + (1u << sh));
    lo = nlo;
    __syncthreads();
  }
  return lo;
}

__global__ __launch_bounds__(1024) void k_fsel(u32* __restrict__ ws) {
  __shared__ u32 h[8192];
  __shared__ u32 aux[40];
  u32* st = ws + WS_STATE / 4;
  const u64* cand = reinterpret_cast<const u64*>((const char*)ws + WS_CAND);
  u32 v0, v1;
  if (st[0] == st[1]) {          // both ranks in one coarse bin: zoom candidates
    u32 M = min(st[4], CAP);
    v0 = zoom(cand, M, st[0], st[2], K_RANK, h, aux);
    v1 = zoom(cand, M, st[1], st[2], K_RANK + 1u, h, aux);
  } else {                       // straddle: K = max raw in cb0, K+1 = min raw in cb1
    v0 = st[5];
    v1 = st[6];
  }
  if (threadIdx.x == 0) {
    float w0 = sqrtf(__uint_as_float(v0));
    float w1 = sqrtf(__uint_as_float(v1));
    double dc = 0.75 * (double)w0 + 0.25 * (double)w1;
    *reinterpret_cast<float*>((char*)ws + WS_DC) = (float)dc;
  }
}

__global__ __launch_bounds__(256) void k_rhoS(
    const float4* __restrict__ S4, u32* __restrict__ ws)
{
  __shared__ double redB[4][128];
  int bi, bj; tri_decode(blockIdx.x, bi, bj);
  const int tid = threadIdx.x;
  const int tx = tid & 15, ty = tid >> 4;
  const float dcf = *reinterpret_cast<const float*>((const char*)ws + WS_DC);
  const float inv2 = 1.0f / (dcf * dcf);
  const int ig0 = bi * 128 + ty * 8, jg0 = bj * 128 + tx * 8;
  const bool diag = (bi == bj);
  const float4* tS = S4 + (size_t)blockIdx.x * 4096 + tid;
  float rA[8] = {}, rB[8] = {};
#pragma unroll 4
  for (int q = 0; q < 16; ++q)
    rho_elem(tS[q * 256], q, inv2, diag, ig0, jg0, rA, rB);
  rho_finish(rA, rB, bi, bj, ig0, ws, redB);
}

__global__ __launch_bounds__(256, 4) void k_rhoR(
    const float* __restrict__ X, const float* __restrict__ sq, u32* __restrict__ ws)
{
  __shared__ __align__(16) char smem[33792];
  __shared__ double redB[4][128];
  float (*As)[132] = reinterpret_cast<float(*)[132]>(smem);
  float (*Bs)[132] = reinterpret_cast<float(*)[132]>(smem + 16896);
  int bi, bj; tri_decode(blockIdx.x, bi, bj);
  const int tid = threadIdx.x;
  const int tx = tid & 15, ty = tid >> 4;
  float d2[8][8];
  tile128(X, sq, As, Bs, bi, bj, tx, ty, d2);
  const float dcf = *reinterpret_cast<const float*>((const char*)ws + WS_DC);
  const float inv2 = 1.0f / (dcf * dcf);
  const int ig0 = bi * 128 + ty * 8, jg0 = bj * 128 + tx * 8;
  const bool diag = (bi == bj);
  float rA[8] = {}, rB[8] = {};
#pragma unroll
  for (int q = 0; q < 16; ++q) {
    int r = q >> 1, c0 = (q & 1) * 4;
    float4 v = make_float4(d2[r][c0+0], d2[r][c0+1], d2[r][c0+2], d2[r][c0+3]);
    rho_elem(v, q, inv2, diag, ig0, jg0, rA, rB);
  }
  rho_finish(rA, rB, bi, bj, ig0, ws, redB);
}

__global__ __launch_bounds__(256) void k_deltaS(
    const float4* __restrict__ S4, u32* __restrict__ ws)
{
  __shared__ u64 redM[4][128];
  int bi, bj; tri_decode(blockIdx.x, bi, bj);
  const int tid = threadIdx.x;
  const int tx = tid & 15, ty = tid >> 4;
  const double* rhod = reinterpret_cast<const double*>((const char*)ws + WS_RHOD);
  const int ig0 = bi * 128 + ty * 8, jg0 = bj * 128 + tx * 8;
  float ri[8], rj[8];
#pragma unroll
  for (int r = 0; r < 8; ++r) ri[r] = (float)rhod[ig0 + r];
#pragma unroll
  for (int c = 0; c < 8; ++c) rj[c] = (float)rhod[jg0 + c];
  u64 bA[8], bB[8];
#pragma unroll
  for (int r = 0; r < 8; ++r) { bA[r] = ~0ull; bB[r] = ~0ull; }
  const bool offd = (bi < bj);
  const float4* tS = S4 + (size_t)blockIdx.x * 4096 + tid;
#pragma unroll 4
  for (int q = 0; q < 16; ++q)
    delta_elem(tS[q * 256], q, offd, ig0, jg0, ri, rj, bA, bB);
  delta_finish(bA, bB, bi, bj, ig0, ws, redM);
}

__global__ __launch_bounds__(256, 4) void k_deltaR(
    const float* __restrict__ X, const float* __restrict__ sq, u32* __restrict__ ws)
{
  __shared__ __align__(16) char smem[33792];
  __shared__ u64 redM[4][128];
  float (*As)[132] = reinterpret_cast<float(*)[132]>(smem);
  float (*Bs)[132] = reinterpret_cast<float(*)[132]>(smem + 16896);
  int bi, bj; tri_decode(blockIdx.x, bi, bj);
  const int tid = threadIdx.x;
  const int tx = tid & 15, ty = tid >> 4;
  float d2[8][8];
  tile128(X, sq, As, Bs, bi, bj, tx, ty, d2);
  const double* rhod = reinterpret_cast<const double*>((const char*)ws + WS_RHOD);
  const int ig0 = bi * 128 + ty * 8, jg0 = bj * 128 + tx * 8;
  float ri[8], rj[8];
#pragma unroll
  for (int r = 0; r < 8; ++r) ri[r] = (float)rhod[ig0 + r];
#pragma unroll
  for (int c = 0; c < 8; ++c) rj[c] = (float)rhod[jg0 + c];
  u64 bA[8], bB[8];
#pragma unroll
  for (int r = 0; r < 8; ++r) { bA[r] = ~0ull; bB[r] = ~0ull; }
  const bool offd = (bi < bj);
#pragma unroll
  for (int q = 0; q < 16; ++q) {
    int r = q >> 1, c0 = (q & 1) * 4;
    float4 v = make_float4(d2[r][c0+0], d2[r][c0+1], d2[r][c0+2], d2[r][c0+3]);
    delta_elem(v, q, offd, ig0, jg0, ri, rj, bA, bB);
  }
  delta_finish(bA, bB, bi, bj, ig0, ws, redM);
}

// labels via pointer doubling (13 rounds, absorbing at labeled/self nodes)
__global__ __launch_bounds__(1024) void k_labels(
    const u32* __restrict__ ws, const float* __restrict__ rtp,
    const float* __restrict__ dtp, int* __restrict__ out)
{
  __shared__ int   nxt[NPTS];
  __shared__ short lab0[NPTS];
  __shared__ u32   aux[40];
  const int t = threadIdx.x;
  const float rt = rtp[0], dt = dtp[0];
  const u64* mk = reinterpret_cast<const u64*>((const char*)ws + WS_MINKEY);
  const u32* rowmax = ws + WS_ROWMAX / 4;
  const double* rhod = reinterpret_cast<const double*>((const char*)ws + WS_RHOD);
  u32 cnt = 0;
  short loc[8];
  int nh_l[8];
#pragma unroll
  for (int e = 0; e < 8; ++e) {
    int i = t * 8 + e;
    u64 key = mk[i];
    bool hh = (key != ~0ull);
    float delta = hh ? __uint_as_float((u32)(key >> 32))
                     : sqrtf(__uint_as_float(rowmax[i]));
    nh_l[e] = hh ? (int)(u32)(key & 0xffffffffull) : i;
    bool isc = ((float)rhod[i] > rt) && (delta > dt);
    loc[e] = isc ? (short)cnt : (short)-1;
    cnt += isc ? 1u : 0u;
  }
  u32 total;
  u32 base = block_exscan_1024(cnt, aux, total);
#pragma unroll
  for (int e = 0; e < 8; ++e) {
    int i = t * 8 + e;
    short lb = (loc[e] >= 0) ? (short)(loc[e] + (int)base) : (short)-1;
    lab0[i] = lb;
    nxt[i] = (lb >= 0 || nh_l[e] == i) ? i : nh_l[e];
  }
  __syncthreads();
  for (int it = 0; it < 13; ++it) {
#pragma unroll
    for (int e = 0; e < 8; ++e) {
      int i = t * 8 + e;
      nxt[i] = nxt[nxt[i]];
    }
    __syncthreads();
  }
#pragma unroll
  for (int e = 0; e < 8; ++e) {
    int i = t * 8 + e;
    out[i] = (int)lab0[nxt[i]];
  }
}

extern "C" void kernel_launch(void* const* d_in, const int* in_sizes, int n_in,
                              void* d_out, int out_size, void* d_ws, size_t ws_size,
                              hipStream_t stream)
{
  (void)in_sizes; (void)n_in; (void)out_size;
  const float* X  = (const float*)d_in[0];
  const float* rt = (const float*)d_in[1];
  const float* dt = (const float*)d_in[2];
  int* out = (int*)d_out;
  u32* ws = (u32*)d_ws;
  float* sq = (float*)((char*)d_ws + WS_SQ);

  const bool big = ws_size >= (size_t)(WS_S + (u64)NTRI * 16384ull * 4ull);
  float4* S4 = big ? reinterpret_cast<float4*>((char*)d_ws + WS_S) : nullptr;

  k_init<<<64, 256, 0, stream>>>(ws);
  k_sq<<<32, 256, 0, stream>>>(X, sq);

  k_hist<<<NTRI, 256, 0, stream>>>(X, sq, ws, S4);
  k_sel1<<<1, 1024, 0, stream>>>(ws);
  if (big) k_collectS<<<NTRI, 256, 0, stream>>>(S4, ws);
  else     k_collectR<<<NTRI, 256, 0, stream>>>(X, sq, ws);
  k_fsel<<<1, 1024, 0, stream>>>(ws);
  if (big) k_rhoS<<<NTRI, 256, 0, stream>>>(S4, ws);
  else     k_rhoR<<<NTRI, 256, 0, stream>>>(X, sq, ws);
  if (big) k_deltaS<<<NTRI, 256, 0, stream>>>(S4, ws);
  else     k_deltaR<<<NTRI, 256, 0, stream>>>(X, sq, ws);
  k_labels<<<1, 1024, 0, stream>>>(ws, rt, dt, out);
}